// Round 9
// baseline (433.447 us; speedup 1.0000x reference)
//
#include <hip/hip_runtime.h>
#include <math.h>
#include <stdint.h>

#define ND_ROWS 16384
#define DDIM    256
#define KCODES  8192
#define NSEG    128        // 64-code segments
#define NRG     8          // row groups (XCD-affine), 2048 rows each

typedef _Float16 f16x4 __attribute__((ext_vector_type(4)));
typedef _Float16 f16x8 __attribute__((ext_vector_type(8)));
typedef float    f32x4 __attribute__((ext_vector_type(4)));

// ---------------------------------------------------------------------------
// ws layout (bytes):
//   minpair [0,        131072)   u64[16384]  (memset 0xFF each call)
//   counts  [131072,   163840)   int[8192]   (memset 0 each call)
//   parts   [163840,   196608)   de[4096] | dq[4096]
//   ne      [196608,   229376)   float[8192]
//   Ap      [229376,   17006592) FRAGMENT-MAJOR A, 16.8 MB:
//            A[rb][kq][rl][8 f16], rb=row/64, rl=row%64, kq 0..31 = hi k-chunks,
//            kq 32..63 = lo. byte addr = rb*65536 + kq*1024 + rl*16.
//   Bp      [17006592, 25395200) 8192 x 512 f16  ([e_hi(256) | e_lo(256)])
// ---------------------------------------------------------------------------

__device__ __attribute__((always_inline)) inline void load_lds16(const void* g, void* l) {
    __builtin_amdgcn_global_load_lds((const __attribute__((address_space(1))) void*)g,
                                     (__attribute__((address_space(3))) void*)l, 16, 0, 0);
}

// one wave per vector: fp16 hi/lo split. A -> fragment-major layout (so the
// argmin kernel's A-fragment loads are fully coalesced); B -> row-major 1KB.
__global__ __launch_bounds__(256) void prep_kernel(const float* __restrict__ x,
                                                   const float* __restrict__ emb,
                                                   _Float16* __restrict__ Ap,
                                                   _Float16* __restrict__ Bp,
                                                   float* __restrict__ ne) {
    int wave = (blockIdx.x << 2) + (threadIdx.x >> 6);   // [0, 24576)
    int lane = threadIdx.x & 63;
    if (wave < ND_ROWS) {
        const float* src = x + (size_t)wave * DDIM;
        float4 v = ((const float4*)src)[lane];
        f16x4 hi, lo;
        hi[0] = (_Float16)v.x; lo[0] = (_Float16)(v.x - (float)hi[0]);
        hi[1] = (_Float16)v.y; lo[1] = (_Float16)(v.y - (float)hi[1]);
        hi[2] = (_Float16)v.z; lo[2] = (_Float16)(v.z - (float)hi[2]);
        hi[3] = (_Float16)v.w; lo[3] = (_Float16)(v.w - (float)hi[3]);
        // lane covers halves [lane*4, lane*4+4): kq = lane>>1, pos = (lane&1)*4
        _Float16* dst = Ap + ((size_t)(wave >> 6) << 15)      // rb * 32768 f16
                           + ((lane >> 1) << 9)               // kq * 512 f16
                           + ((wave & 63) << 3)               // rl * 8 f16
                           + ((lane & 1) << 2);
        *(f16x4*)dst           = hi;
        *(f16x4*)(dst + 16384) = lo;                          // +32*512 f16
    } else {
        int r = wave - ND_ROWS;
        const float* src = emb + (size_t)r * DDIM;
        _Float16* dst = Bp + (size_t)r * 512;
        float4 v = ((const float4*)src)[lane];
        f16x4 hi, lo;
        hi[0] = (_Float16)v.x; lo[0] = (_Float16)(v.x - (float)hi[0]);
        hi[1] = (_Float16)v.y; lo[1] = (_Float16)(v.y - (float)hi[1]);
        hi[2] = (_Float16)v.z; lo[2] = (_Float16)(v.z - (float)hi[2]);
        hi[3] = (_Float16)v.w; lo[3] = (_Float16)(v.w - (float)hi[3]);
        *(f16x4*)(dst + lane * 4)       = hi;
        *(f16x4*)(dst + 256 + lane * 4) = lo;
        float s = v.x*v.x + v.y*v.y + v.z*v.z + v.w*v.w;
        #pragma unroll
        for (int m = 32; m; m >>= 1) s += __shfl_xor(s, m, 64);
        if (lane == 0) ne[r] = s;
    }
}

// Barrier-free argmin GEMM. Block = (rgroup = blockIdx&7 [XCD-affine rows],
// seg = blockIdx>>3 [64 codes]). B slab (64 codes x [hi|lo] = 64 KB) staged to
// LDS ONCE (single barrier); A streamed from L2 via fully-coalesced
// fragment-major dwordx4 loads (the R7 fix). K-loop has NO barriers, so the
// compiler pipelines global loads across MFMAs with fine-grained vmcnt(N) --
// the structure the 2-barrier K-loop (m97 plateau, R6/R8) cannot express.
// dot = x1.e1 + x1.e2 + x2.e1; dist' = ne - 2*dot (||x||^2 dropped).
// Cross-block merge: packed u64 atomicMin, XCD-local lines (rgroup-partitioned).
__global__ __launch_bounds__(256, 2) void argmin_seg(
    const _Float16* __restrict__ Ap, const _Float16* __restrict__ Bp,
    const float* __restrict__ ne, unsigned long long* __restrict__ minpair) {
    __shared__ __align__(16) _Float16 Bs[64 * 512];   // 64 KB (fills the 64 KB cap)

    const int tid  = threadIdx.x;
    const int lane = tid & 63;
    const int w    = tid >> 6;   // 0..3
    const int quad = lane >> 4;
    const int t16  = lane & 15;

    const int rgroup  = blockIdx.x & 7;
    const int seg     = blockIdx.x >> 3;
    const int rowBase = rgroup * 2048;
    const int code0   = seg * 64;

    // stage B slab: wave w stages codes [w*16, w*16+16); per instr lane l ->
    // phys slot l (HW: base + l*16) holding logical chunk l ^ (cl&7).
    #pragma unroll
    for (int i = 0; i < 16; ++i) {
        int cl = w * 16 + i;
        int g  = lane ^ (cl & 7);
        const char* gB = (const char*)(Bp + (size_t)(code0 + cl) * 512) + g * 16;
        load_lds16(gB, (char*)Bs + cl * 1024);
    }
    float nec[4];
    #pragma unroll
    for (int nt = 0; nt < 4; ++nt) nec[nt] = ne[code0 + nt * 16 + t16];
    __syncthreads();   // the only barrier

    const int s7 = t16 & 7;

    // wave w owns rows [rowBase + w*512, +512) in 8 chunks of 64
    for (int c = 0; c < 8; ++c) {
        const int m0 = rowBase + w * 512 + c * 64;
        const char* pH = (const char*)Ap + ((size_t)(m0 >> 6) << 16)
                       + (quad << 10) + (t16 << 4);
        f32x4 acc[4][4];
        #pragma unroll
        for (int mt = 0; mt < 4; ++mt)
            #pragma unroll
            for (int nt = 0; nt < 4; ++nt) {
                f32x4 z = {0.0f, 0.0f, 0.0f, 0.0f};
                acc[mt][nt] = z;
            }

        #pragma unroll 2
        for (int kc = 0; kc < 8; ++kc) {
            const char* pa = pH + (kc << 12);
            f16x8 ah[4], al[4], bh[4], bl[4];
            #pragma unroll
            for (int mt = 0; mt < 4; ++mt) {
                ah[mt] = *(const f16x8*)(pa + (mt << 8));            // hi kq
                al[mt] = *(const f16x8*)(pa + 32768 + (mt << 8));    // lo kq (+32*1024B)
            }
            #pragma unroll
            for (int nt = 0; nt < 4; ++nt) {
                int cb = (nt * 16 + t16) * 1024;
                bh[nt] = *(const f16x8*)((const char*)Bs + cb + (((kc * 4 + quad) ^ s7) << 4));
                bl[nt] = *(const f16x8*)((const char*)Bs + cb + (((32 + kc * 4 + quad) ^ s7) << 4));
            }
            #pragma unroll
            for (int mt = 0; mt < 4; ++mt)   // hh
                #pragma unroll
                for (int nt = 0; nt < 4; ++nt)
                    acc[mt][nt] = __builtin_amdgcn_mfma_f32_16x16x32_f16(ah[mt], bh[nt], acc[mt][nt], 0, 0, 0);
            #pragma unroll
            for (int mt = 0; mt < 4; ++mt)   // hl
                #pragma unroll
                for (int nt = 0; nt < 4; ++nt)
                    acc[mt][nt] = __builtin_amdgcn_mfma_f32_16x16x32_f16(ah[mt], bl[nt], acc[mt][nt], 0, 0, 0);
            #pragma unroll
            for (int mt = 0; mt < 4; ++mt)   // lh (bh still in registers)
                #pragma unroll
                for (int nt = 0; nt < 4; ++nt)
                    acc[mt][nt] = __builtin_amdgcn_mfma_f32_16x16x32_f16(al[mt], bh[nt], acc[mt][nt], 0, 0, 0);
        }

        // epilogue: per row-register, argmin over 64 codes (nt ascending +
        // strict < + t16-shuffle with idx tiebreak => first-wins), then one
        // XCD-local packed atomicMin per row.
        #pragma unroll
        for (int mt = 0; mt < 4; ++mt)
            #pragma unroll
            for (int r = 0; r < 4; ++r) {
                float best = nec[0] - 2.0f * acc[mt][0][r];
                int   bi   = code0 + t16;
                #pragma unroll
                for (int nt = 1; nt < 4; ++nt) {
                    float d = nec[nt] - 2.0f * acc[mt][nt][r];
                    if (d < best) { best = d; bi = code0 + nt * 16 + t16; }
                }
                #pragma unroll
                for (int m = 1; m < 16; m <<= 1) {
                    float ov = __shfl_xor(best, m, 64);
                    int   oi = __shfl_xor(bi, m, 64);
                    if (ov < best || (ov == best && oi < bi)) { best = ov; bi = oi; }
                }
                if (t16 == 0) {
                    int row = m0 + mt * 16 + quad * 4 + r;
                    unsigned u = __float_as_uint(best);
                    u = (u & 0x80000000u) ? ~u : (u | 0x80000000u);   // total-order map
                    unsigned long long packed = ((unsigned long long)u << 32) | (unsigned)bi;
                    atomicMin(&minpair[row], packed);
                }
            }
    }
}

// decode packed min, gather codebook row, write quantized_sg + float index,
// histogram atomic + per-block SSE partials.
__global__ __launch_bounds__(256) void finalize_kernel(
    const float* __restrict__ x, const float* __restrict__ emb,
    const unsigned long long* __restrict__ minpair,
    float* __restrict__ out_q, float* __restrict__ out_idx,
    int* __restrict__ counts, float* __restrict__ parts) {
    __shared__ float rde[4], rdq[4];
    int wv   = threadIdx.x >> 6;
    int row  = (blockIdx.x << 2) + wv;
    int lane = threadIdx.x & 63;

    int bi = (int)(minpair[row] & 0xFFFFFFFFull);

    float4 xv = ((const float4*)(x   + (size_t)row * DDIM))[lane];
    float4 ev = ((const float4*)(emb + (size_t)bi  * DDIM))[lane];
    float4 q;
    q.x = xv.x + (ev.x - xv.x);
    q.y = xv.y + (ev.y - xv.y);
    q.z = xv.z + (ev.z - xv.z);
    q.w = xv.w + (ev.w - xv.w);
    ((float4*)(out_q + (size_t)row * DDIM))[lane] = q;

    float de = (ev.x - xv.x) * (ev.x - xv.x) + (ev.y - xv.y) * (ev.y - xv.y)
             + (ev.z - xv.z) * (ev.z - xv.z) + (ev.w - xv.w) * (ev.w - xv.w);
    float dq = (q.x - ev.x) * (q.x - ev.x) + (q.y - ev.y) * (q.y - ev.y)
             + (q.z - ev.z) * (q.z - ev.z) + (q.w - ev.w) * (q.w - ev.w);
    #pragma unroll
    for (int m = 32; m; m >>= 1) {
        de += __shfl_xor(de, m, 64);
        dq += __shfl_xor(dq, m, 64);
    }
    if (lane == 0) {
        out_idx[row] = (float)bi;
        atomicAdd(&counts[bi], 1);
        rde[wv] = de; rdq[wv] = dq;
    }
    __syncthreads();
    if (threadIdx.x == 0) {
        parts[blockIdx.x]        = rde[0] + rde[1] + rde[2] + rde[3];
        parts[4096 + blockIdx.x] = rdq[0] + rdq[1] + rdq[2] + rdq[3];
    }
}

__global__ __launch_bounds__(256) void scalars_kernel(
    const int* __restrict__ counts, const float* __restrict__ parts,
    float* __restrict__ out_loss, float* __restrict__ out_perp) {
    __shared__ float red[256], rde[256], rdq[256];
    float local = 0.0f, de = 0.0f, dq = 0.0f;
    for (int k = threadIdx.x; k < KCODES; k += 256) {
        float p = (float)counts[k] * (1.0f / (float)ND_ROWS);
        local += p * logf(p + 1e-10f);
    }
    for (int k = threadIdx.x; k < 4096; k += 256) {
        de += parts[k];
        dq += parts[4096 + k];
    }
    red[threadIdx.x] = local; rde[threadIdx.x] = de; rdq[threadIdx.x] = dq;
    __syncthreads();
    for (int s = 128; s; s >>= 1) {
        if (threadIdx.x < s) {
            red[threadIdx.x] += red[threadIdx.x + s];
            rde[threadIdx.x] += rde[threadIdx.x + s];
            rdq[threadIdx.x] += rdq[threadIdx.x + s];
        }
        __syncthreads();
    }
    if (threadIdx.x == 0) {
        *out_perp = expf(-red[0]);
        float invn = 1.0f / (float)(ND_ROWS * DDIM);
        *out_loss = rdq[0] * invn + 0.25f * (rde[0] * invn);
    }
}

extern "C" void kernel_launch(void* const* d_in, const int* in_sizes, int n_in,
                              void* d_out, int out_size, void* d_ws, size_t ws_size,
                              hipStream_t stream) {
    const float* x   = (const float*)d_in[0];
    const float* emb = (const float*)d_in[1];

    char* ws = (char*)d_ws;
    unsigned long long* minpair = (unsigned long long*)ws;         // 128 KB
    int*      counts = (int*)(ws + 131072);                        // 32 KB
    float*    parts  = (float*)(ws + 163840);                      // 32 KB
    float*    ne     = (float*)(ws + 196608);                      // 32 KB
    _Float16* Ap     = (_Float16*)(ws + 229376);                   // 16.8 MB
    _Float16* Bp     = (_Float16*)(ws + 17006592);                 // 8.4 MB

    float* out_q    = (float*)d_out;
    float* out_idx  = out_q + (size_t)ND_ROWS * DDIM;
    float* out_loss = out_idx + ND_ROWS;
    float* out_perp = out_loss + 1;

    hipMemsetAsync(minpair, 0xFF, ND_ROWS * sizeof(unsigned long long), stream);
    hipMemsetAsync(counts, 0, KCODES * sizeof(int), stream);

    prep_kernel<<<(KCODES + ND_ROWS) / 4, 256, 0, stream>>>(x, emb, Ap, Bp, ne);
    argmin_seg<<<NRG * NSEG, 256, 0, stream>>>(Ap, Bp, ne, minpair);
    finalize_kernel<<<ND_ROWS / 4, 256, 0, stream>>>(x, emb, minpair,
                                                     out_q, out_idx, counts, parts);
    scalars_kernel<<<1, 256, 0, stream>>>(counts, parts, out_loss, out_perp);
}

// Round 11
// 312.943 us; speedup vs baseline: 1.3851x; 1.3851x over previous
//
#include <hip/hip_runtime.h>
#include <math.h>
#include <stdint.h>

#define ND_ROWS 16384
#define DDIM    256
#define KCODES  8192
#define NSEG    128        // 64-code segments
#define NRG     8          // row groups (XCD-affine), 2048 rows each

typedef _Float16 f16x4 __attribute__((ext_vector_type(4)));
typedef _Float16 f16x8 __attribute__((ext_vector_type(8)));
typedef float    f32x4v __attribute__((ext_vector_type(4)));
typedef float    f32x16 __attribute__((ext_vector_type(16)));

// ---------------------------------------------------------------------------
// ws layout (bytes):
//   minpair [0,        131072)   u64[16384]  (memset 0xFF each call)
//   counts  [131072,   163840)   int[8192]   (memset 0 each call)
//   parts   [163840,   196608)   de[4096] | dq[4096]
//   neF     [196608,   229376)   float[8192] = ||e||^2
//   Xp      [229376,   17006592) x as MFMA B-operand fragments, 16.8 MB:
//            per 32-row block rb (32 KB): hi q=0..15 then lo q=0..15; unit
//            (rb,q) = 1 KB; 16B chunk index within unit = (kg<<5)|rl holding
//            halves k = q*16 + kg*8 .. +8 of row rl. (coalesced 1KB/instr)
//   Bp      [17006592, 25395200) 8192 x 512 f16 = [-2e_hi(256) | -2e_lo(256)]
// ---------------------------------------------------------------------------

__device__ __attribute__((always_inline)) inline void load_lds16(const void* g, void* l) {
    __builtin_amdgcn_global_load_lds((const __attribute__((address_space(1))) void*)g,
                                     (__attribute__((address_space(3))) void*)l, 16, 0, 0);
}

// one wave per vector. x -> B-operand fragment layout (hi/lo split, unscaled).
// codebook -> row-major [-2e_hi | -2e_lo] (-2 folded in) + float ne table.
__global__ __launch_bounds__(256) void prep_kernel(const float* __restrict__ x,
                                                   const float* __restrict__ emb,
                                                   _Float16* __restrict__ Xp,
                                                   _Float16* __restrict__ Bp,
                                                   float* __restrict__ neF) {
    int wave = (blockIdx.x << 2) + (threadIdx.x >> 6);   // [0, 24576)
    int lane = threadIdx.x & 63;
    if (wave < ND_ROWS) {
        const float* src = x + (size_t)wave * DDIM;
        float4 v = ((const float4*)src)[lane];           // k = lane*4 .. +4
        f16x4 hi, lo;
        hi[0] = (_Float16)v.x; lo[0] = (_Float16)(v.x - (float)hi[0]);
        hi[1] = (_Float16)v.y; lo[1] = (_Float16)(v.y - (float)hi[1]);
        hi[2] = (_Float16)v.z; lo[2] = (_Float16)(v.z - (float)hi[2]);
        hi[3] = (_Float16)v.w; lo[3] = (_Float16)(v.w - (float)hi[3]);
        int rb = wave >> 5, rl = wave & 31;
        // q = lane>>2, kg = (lane>>1)&1, j0 = (lane&1)*4  (f16-unit offsets)
        size_t off = (size_t)rb * 16384 + ((lane >> 2) << 9)
                   + (((lane >> 1) & 1) << 8) + (rl << 3) + ((lane & 1) << 2);
        *(f16x4*)(Xp + off)        = hi;
        *(f16x4*)(Xp + off + 8192) = lo;                 // lo block: +16 KB
    } else {
        int r = wave - ND_ROWS;
        const float* src = emb + (size_t)r * DDIM;
        float4 v = ((const float4*)src)[lane];
        float s = v.x*v.x + v.y*v.y + v.z*v.z + v.w*v.w;  // ||e||^2 of original e
        #pragma unroll
        for (int m = 32; m; m >>= 1) s += __shfl_xor(s, m, 64);
        float4 t;                                         // fold the -2 in
        t.x = -2.0f * v.x; t.y = -2.0f * v.y; t.z = -2.0f * v.z; t.w = -2.0f * v.w;
        f16x4 hi, lo;
        hi[0] = (_Float16)t.x; lo[0] = (_Float16)(t.x - (float)hi[0]);
        hi[1] = (_Float16)t.y; lo[1] = (_Float16)(t.y - (float)hi[1]);
        hi[2] = (_Float16)t.z; lo[2] = (_Float16)(t.z - (float)hi[2]);
        hi[3] = (_Float16)t.w; lo[3] = (_Float16)(t.w - (float)hi[3]);
        _Float16* dst = Bp + (size_t)r * 512;
        *(f16x4*)(dst + lane * 4)       = hi;
        *(f16x4*)(dst + 256 + lane * 4) = lo;
        if (lane == 0) neF[r] = s;
    }
}

// Barrier-free argmin GEMM, codes-as-M, mfma_f32_32x32x16_f16.
// Block = (rgroup = blockIdx&7 [2048 XCD-affine rows], seg = blockIdx>>3
// [64 codes]). Code slab (-2e hi/lo) = EXACTLY 64 KB LDS (the 64KB workgroup
// cap killed R10's 66KB variant). ne enters via 32 preloaded registers per
// lane (each lane's 32 output code-ids are block-constant). x streamed from
// L2 via coalesced fragment loads; K-loop has NO barriers.
// Epilogue: d = acc + ne, in-lane ascending-code scan, ONE xor-32 shuffle,
// packed u64 atomicMin (flip(dist)<<32 | idx; tie -> smaller index).
__global__ __launch_bounds__(512, 4) void argmin_seg(
    const _Float16* __restrict__ Xp, const _Float16* __restrict__ Bp,
    const float* __restrict__ neF, unsigned long long* __restrict__ minpair) {
    __shared__ __align__(16) _Float16 Cs[64 * 512];   // 64 KB, nothing else

    const int tid  = threadIdx.x;
    const int lane = tid & 63;
    const int w    = tid >> 6;     // 0..7
    const int c32  = lane & 31;
    const int kg   = lane >> 5;

    const int rg      = blockIdx.x & 7;
    const int seg     = blockIdx.x >> 3;
    const int rowBase = rg * 2048;
    const int code0   = seg * 64;

    // stage code slab: wave w -> codes [w*8, w*8+8); per instr lane l is phys
    // 16B slot l, fetching logical chunk l ^ (code&7) (XOR bank swizzle).
    #pragma unroll
    for (int i = 0; i < 8; ++i) {
        int cl = w * 8 + i;
        int g  = lane ^ (cl & 7);
        load_lds16((const char*)(Bp + (size_t)(code0 + cl) * 512) + g * 16,
                   (char*)Cs + cl * 1024);
    }
    // preload this lane's 32 ne values: id(mt,r) = code0 + mt*32 + 4kg +
    // (r&3) + 8*(r>>2)  ->  ne4[mt][g2] = neF[code0 + mt*32 + g2*8 + 4*kg .. +4]
    f32x4v ne4[2][4];
    #pragma unroll
    for (int mt = 0; mt < 2; ++mt)
        #pragma unroll
        for (int g2 = 0; g2 < 4; ++g2)
            ne4[mt][g2] = *(const f32x4v*)(neF + code0 + mt * 32 + g2 * 8 + 4 * kg);
    __syncthreads();   // the only barrier

    const int wBase = rowBase + w * 256;   // 8 chunks of 32 rows per wave
    for (int c = 0; c < 8; ++c) {
        const int rb = (wBase >> 5) + c;
        const char* xb = (const char*)Xp + (size_t)rb * 32768 + lane * 16;
        f32x16 acc[2];
        #pragma unroll
        for (int i = 0; i < 16; ++i) { acc[0][i] = 0.0f; acc[1][i] = 0.0f; }

        #pragma unroll 2
        for (int q = 0; q < 16; ++q) {
            f16x8 xh = *(const f16x8*)(xb + q * 1024);
            f16x8 xl = *(const f16x8*)(xb + 16384 + q * 1024);
            f16x8 ch[2], cl2[2];
            #pragma unroll
            for (int mt = 0; mt < 2; ++mt) {
                const char* cp = (const char*)Cs + (mt * 32 + c32) * 1024;
                int ph = (q * 2 + kg) ^ (c32 & 7);
                int pl = (32 + q * 2 + kg) ^ (c32 & 7);
                ch[mt]  = *(const f16x8*)(cp + ph * 16);
                cl2[mt] = *(const f16x8*)(cp + pl * 16);
            }
            acc[0] = __builtin_amdgcn_mfma_f32_32x32x16_f16(ch[0],  xh, acc[0], 0, 0, 0);
            acc[1] = __builtin_amdgcn_mfma_f32_32x32x16_f16(ch[1],  xh, acc[1], 0, 0, 0);
            acc[0] = __builtin_amdgcn_mfma_f32_32x32x16_f16(ch[0],  xl, acc[0], 0, 0, 0);
            acc[1] = __builtin_amdgcn_mfma_f32_32x32x16_f16(ch[1],  xl, acc[1], 0, 0, 0);
            acc[0] = __builtin_amdgcn_mfma_f32_32x32x16_f16(cl2[0], xh, acc[0], 0, 0, 0);
            acc[1] = __builtin_amdgcn_mfma_f32_32x32x16_f16(cl2[1], xh, acc[1], 0, 0, 0);
        }

        // epilogue: acc[mt][r] + ne = dist(code id(mt,r), row rb*32 + c32).
        // (mt,r) ascending <=> code id ascending within lane; strict < =>
        // first(lowest-index)-wins. Then one xor-32 merge (tie -> smaller idx).
        float best = 3.402823466e+38f;
        int   bi   = 0;
        #pragma unroll
        for (int mt = 0; mt < 2; ++mt)
            #pragma unroll
            for (int r = 0; r < 16; ++r) {
                float d  = acc[mt][r] + ne4[mt][r >> 2][r & 3];
                int   id = code0 + mt * 32 + 4 * kg + ((r & 3) + 8 * (r >> 2));
                if (d < best) { best = d; bi = id; }
            }
        float ov = __shfl_xor(best, 32, 64);
        int   oi = __shfl_xor(bi, 32, 64);
        if (ov < best || (ov == best && oi < bi)) { best = ov; bi = oi; }
        if (kg == 0) {
            int row = rb * 32 + c32;
            unsigned u = __float_as_uint(best);
            u = (u & 0x80000000u) ? ~u : (u | 0x80000000u);   // total-order map
            atomicMin(&minpair[row],
                      (((unsigned long long)u) << 32) | (unsigned)bi);
        }
    }
}

// decode packed min, gather codebook row, write quantized_sg + float index,
// histogram atomic + per-block SSE partials.
__global__ __launch_bounds__(256) void finalize_kernel(
    const float* __restrict__ x, const float* __restrict__ emb,
    const unsigned long long* __restrict__ minpair,
    float* __restrict__ out_q, float* __restrict__ out_idx,
    int* __restrict__ counts, float* __restrict__ parts) {
    __shared__ float rde[4], rdq[4];
    int wv   = threadIdx.x >> 6;
    int row  = (blockIdx.x << 2) + wv;
    int lane = threadIdx.x & 63;

    int bi = (int)(minpair[row] & 0xFFFFFFFFull);

    float4 xv = ((const float4*)(x   + (size_t)row * DDIM))[lane];
    float4 ev = ((const float4*)(emb + (size_t)bi  * DDIM))[lane];
    float4 q;
    q.x = xv.x + (ev.x - xv.x);
    q.y = xv.y + (ev.y - xv.y);
    q.z = xv.z + (ev.z - xv.z);
    q.w = xv.w + (ev.w - xv.w);
    ((float4*)(out_q + (size_t)row * DDIM))[lane] = q;

    float de = (ev.x - xv.x) * (ev.x - xv.x) + (ev.y - xv.y) * (ev.y - xv.y)
             + (ev.z - xv.z) * (ev.z - xv.z) + (ev.w - xv.w) * (ev.w - xv.w);
    float dq = (q.x - ev.x) * (q.x - ev.x) + (q.y - ev.y) * (q.y - ev.y)
             + (q.z - ev.z) * (q.z - ev.z) + (q.w - ev.w) * (q.w - ev.w);
    #pragma unroll
    for (int m = 32; m; m >>= 1) {
        de += __shfl_xor(de, m, 64);
        dq += __shfl_xor(dq, m, 64);
    }
    if (lane == 0) {
        out_idx[row] = (float)bi;
        atomicAdd(&counts[bi], 1);
        rde[wv] = de; rdq[wv] = dq;
    }
    __syncthreads();
    if (threadIdx.x == 0) {
        parts[blockIdx.x]        = rde[0] + rde[1] + rde[2] + rde[3];
        parts[4096 + blockIdx.x] = rdq[0] + rdq[1] + rdq[2] + rdq[3];
    }
}

__global__ __launch_bounds__(256) void scalars_kernel(
    const int* __restrict__ counts, const float* __restrict__ parts,
    float* __restrict__ out_loss, float* __restrict__ out_perp) {
    __shared__ float red[256], rde[256], rdq[256];
    float local = 0.0f, de = 0.0f, dq = 0.0f;
    for (int k = threadIdx.x; k < KCODES; k += 256) {
        float p = (float)counts[k] * (1.0f / (float)ND_ROWS);
        local += p * logf(p + 1e-10f);
    }
    for (int k = threadIdx.x; k < 4096; k += 256) {
        de += parts[k];
        dq += parts[4096 + k];
    }
    red[threadIdx.x] = local; rde[threadIdx.x] = de; rdq[threadIdx.x] = dq;
    __syncthreads();
    for (int s = 128; s; s >>= 1) {
        if (threadIdx.x < s) {
            red[threadIdx.x] += red[threadIdx.x + s];
            rde[threadIdx.x] += rde[threadIdx.x + s];
            rdq[threadIdx.x] += rdq[threadIdx.x + s];
        }
        __syncthreads();
    }
    if (threadIdx.x == 0) {
        *out_perp = expf(-red[0]);
        float invn = 1.0f / (float)(ND_ROWS * DDIM);
        *out_loss = rdq[0] * invn + 0.25f * (rde[0] * invn);
    }
}

extern "C" void kernel_launch(void* const* d_in, const int* in_sizes, int n_in,
                              void* d_out, int out_size, void* d_ws, size_t ws_size,
                              hipStream_t stream) {
    const float* x   = (const float*)d_in[0];
    const float* emb = (const float*)d_in[1];

    char* ws = (char*)d_ws;
    unsigned long long* minpair = (unsigned long long*)ws;         // 128 KB
    int*      counts = (int*)(ws + 131072);                        // 32 KB
    float*    parts  = (float*)(ws + 163840);                      // 32 KB
    float*    neF    = (float*)(ws + 196608);                      // 32 KB
    _Float16* Xp     = (_Float16*)(ws + 229376);                   // 16.8 MB
    _Float16* Bp     = (_Float16*)(ws + 17006592);                 // 8.4 MB

    float* out_q    = (float*)d_out;
    float* out_idx  = out_q + (size_t)ND_ROWS * DDIM;
    float* out_loss = out_idx + ND_ROWS;
    float* out_perp = out_loss + 1;

    hipMemsetAsync(minpair, 0xFF, ND_ROWS * sizeof(unsigned long long), stream);
    hipMemsetAsync(counts, 0, KCODES * sizeof(int), stream);

    prep_kernel<<<(KCODES + ND_ROWS) / 4, 256, 0, stream>>>(x, emb, Xp, Bp, neF);
    argmin_seg<<<NRG * NSEG, 512, 0, stream>>>(Xp, Bp, neF, minpair);
    finalize_kernel<<<ND_ROWS / 4, 256, 0, stream>>>(x, emb, minpair,
                                                     out_q, out_idx, counts, parts);
    scalars_kernel<<<1, 256, 0, stream>>>(counts, parts, out_loss, out_perp);
}

// Round 12
// 303.654 us; speedup vs baseline: 1.4274x; 1.0306x over previous
//
#include <hip/hip_runtime.h>
#include <math.h>
#include <stdint.h>

#define ND_ROWS 16384
#define DDIM    256
#define KCODES  8192
#define NSEG    128        // 64-code segments
#define NRG     8          // row groups (XCD-affine), 2048 rows each

typedef _Float16 f16x4 __attribute__((ext_vector_type(4)));
typedef _Float16 f16x8 __attribute__((ext_vector_type(8)));
typedef float    f32x4v __attribute__((ext_vector_type(4)));
typedef float    f32x16 __attribute__((ext_vector_type(16)));

// ---------------------------------------------------------------------------
// ws layout (bytes):
//   minpair [0,        131072)   u64[16384]  (memset 0xFF each call)
//   counts  [131072,   163840)   int[8192]   (memset 0 each call)
//   parts   [163840,   196608)   de[4096] | dq[4096]
//   neF     [196608,   229376)   float[8192] = ||e||^2
//   Xp      [229376,   17006592) x as MFMA B-operand fragments, 16.8 MB:
//            per 32-row block rb (32 KB): hi q=0..15 then lo q=0..15; unit
//            (rb,q) = 1 KB; 16B chunk index within unit = (kg<<5)|rl holding
//            halves k = q*16 + kg*8 .. +8 of row rl. (coalesced 1KB/instr)
//   Bp      [17006592, 25395200) 8192 x 512 f16 = [-2e_hi(256) | -2e_lo(256)]
// ---------------------------------------------------------------------------

__device__ __attribute__((always_inline)) inline void load_lds16(const void* g, void* l) {
    __builtin_amdgcn_global_load_lds((const __attribute__((address_space(1))) void*)g,
                                     (__attribute__((address_space(3))) void*)l, 16, 0, 0);
}

// one wave per vector. x -> B-operand fragment layout (hi/lo split, unscaled).
// codebook -> row-major [-2e_hi | -2e_lo] (-2 folded in) + float ne table.
__global__ __launch_bounds__(256) void prep_kernel(const float* __restrict__ x,
                                                   const float* __restrict__ emb,
                                                   _Float16* __restrict__ Xp,
                                                   _Float16* __restrict__ Bp,
                                                   float* __restrict__ neF) {
    int wave = (blockIdx.x << 2) + (threadIdx.x >> 6);   // [0, 24576)
    int lane = threadIdx.x & 63;
    if (wave < ND_ROWS) {
        const float* src = x + (size_t)wave * DDIM;
        float4 v = ((const float4*)src)[lane];           // k = lane*4 .. +4
        f16x4 hi, lo;
        hi[0] = (_Float16)v.x; lo[0] = (_Float16)(v.x - (float)hi[0]);
        hi[1] = (_Float16)v.y; lo[1] = (_Float16)(v.y - (float)hi[1]);
        hi[2] = (_Float16)v.z; lo[2] = (_Float16)(v.z - (float)hi[2]);
        hi[3] = (_Float16)v.w; lo[3] = (_Float16)(v.w - (float)hi[3]);
        int rb = wave >> 5, rl = wave & 31;
        // q = lane>>2, kg = (lane>>1)&1, j0 = (lane&1)*4  (f16-unit offsets)
        size_t off = (size_t)rb * 16384 + ((lane >> 2) << 9)
                   + (((lane >> 1) & 1) << 8) + (rl << 3) + ((lane & 1) << 2);
        *(f16x4*)(Xp + off)        = hi;
        *(f16x4*)(Xp + off + 8192) = lo;                 // lo block: +16 KB
    } else {
        int r = wave - ND_ROWS;
        const float* src = emb + (size_t)r * DDIM;
        float4 v = ((const float4*)src)[lane];
        float s = v.x*v.x + v.y*v.y + v.z*v.z + v.w*v.w;  // ||e||^2 of original e
        #pragma unroll
        for (int m = 32; m; m >>= 1) s += __shfl_xor(s, m, 64);
        float4 t;                                         // fold the -2 in
        t.x = -2.0f * v.x; t.y = -2.0f * v.y; t.z = -2.0f * v.z; t.w = -2.0f * v.w;
        f16x4 hi, lo;
        hi[0] = (_Float16)t.x; lo[0] = (_Float16)(t.x - (float)hi[0]);
        hi[1] = (_Float16)t.y; lo[1] = (_Float16)(t.y - (float)hi[1]);
        hi[2] = (_Float16)t.z; lo[2] = (_Float16)(t.z - (float)hi[2]);
        hi[3] = (_Float16)t.w; lo[3] = (_Float16)(t.w - (float)hi[3]);
        _Float16* dst = Bp + (size_t)r * 512;
        *(f16x4*)(dst + lane * 4)       = hi;
        *(f16x4*)(dst + 256 + lane * 4) = lo;
        if (lane == 0) neF[r] = s;
    }
}

// Barrier-free argmin GEMM, codes-as-M, mfma_f32_32x32x16_f16, 2-chunk blocked.
// Block = (rgroup = blockIdx&7 [2048 XCD-affine rows], seg = blockIdx>>3
// [64 codes]). Code slab (-2e hi/lo) = exactly 64 KB LDS (the 64 KB cap).
// Per iteration each wave processes 64 rows (2 chunks) against its 64 codes:
// acc[2][2] = 4 INDEPENDENT MFMA chains (R11's 2 chains -> MfmaUtil pinned at
// 50% by 32x32 latency), and each LDS code-fragment read feeds 2x the MFMAs
// (R11 LDS pipe was ~52% busy incl. the structural 4-way b128 conflict).
// ne is loaded in the epilogue only (L1-hot) to keep main-loop VGPRs low.
__global__ __launch_bounds__(512, 4) void argmin_seg(
    const _Float16* __restrict__ Xp, const _Float16* __restrict__ Bp,
    const float* __restrict__ neF, unsigned long long* __restrict__ minpair) {
    __shared__ __align__(16) _Float16 Cs[64 * 512];   // 64 KB, nothing else

    const int tid  = threadIdx.x;
    const int lane = tid & 63;
    const int w    = tid >> 6;     // 0..7
    const int c32  = lane & 31;
    const int kg   = lane >> 5;

    const int rg      = blockIdx.x & 7;
    const int seg     = blockIdx.x >> 3;
    const int rowBase = rg * 2048;
    const int code0   = seg * 64;

    // stage code slab: wave w -> codes [w*8, w*8+8); per instr lane l is phys
    // 16B slot l, fetching logical chunk l ^ (code&7) (XOR bank swizzle).
    #pragma unroll
    for (int i = 0; i < 8; ++i) {
        int cl = w * 8 + i;
        int g  = lane ^ (cl & 7);
        load_lds16((const char*)(Bp + (size_t)(code0 + cl) * 512) + g * 16,
                   (char*)Cs + cl * 1024);
    }
    __syncthreads();   // the only barrier

    const int wBase = rowBase + w * 256;   // 4 chunk-pairs of 64 rows per wave
    for (int c2 = 0; c2 < 4; ++c2) {
        const int rb0 = (wBase >> 5) + c2 * 2;
        const char* xb0 = (const char*)Xp + (size_t)rb0 * 32768 + lane * 16;
        const char* xb1 = xb0 + 32768;
        f32x16 acc[2][2];   // [chunk][mt] - 4 independent chains, 64 AGPR
        #pragma unroll
        for (int i = 0; i < 16; ++i) {
            acc[0][0][i] = 0.0f; acc[0][1][i] = 0.0f;
            acc[1][0][i] = 0.0f; acc[1][1][i] = 0.0f;
        }

        #pragma unroll 2
        for (int q = 0; q < 16; ++q) {
            f16x8 xh0 = *(const f16x8*)(xb0 + q * 1024);
            f16x8 xl0 = *(const f16x8*)(xb0 + 16384 + q * 1024);
            f16x8 xh1 = *(const f16x8*)(xb1 + q * 1024);
            f16x8 xl1 = *(const f16x8*)(xb1 + 16384 + q * 1024);
            f16x8 ch[2], cl2[2];
            #pragma unroll
            for (int mt = 0; mt < 2; ++mt) {
                const char* cp = (const char*)Cs + (mt * 32 + c32) * 1024;
                int ph = (q * 2 + kg) ^ (c32 & 7);
                int pl = (32 + q * 2 + kg) ^ (c32 & 7);
                ch[mt]  = *(const f16x8*)(cp + ph * 16);
                cl2[mt] = *(const f16x8*)(cp + pl * 16);
            }
            // 12 MFMAs, chain-interleaved (each chain's next issue is 4 slots away)
            acc[0][0] = __builtin_amdgcn_mfma_f32_32x32x16_f16(ch[0],  xh0, acc[0][0], 0, 0, 0);
            acc[0][1] = __builtin_amdgcn_mfma_f32_32x32x16_f16(ch[1],  xh0, acc[0][1], 0, 0, 0);
            acc[1][0] = __builtin_amdgcn_mfma_f32_32x32x16_f16(ch[0],  xh1, acc[1][0], 0, 0, 0);
            acc[1][1] = __builtin_amdgcn_mfma_f32_32x32x16_f16(ch[1],  xh1, acc[1][1], 0, 0, 0);
            acc[0][0] = __builtin_amdgcn_mfma_f32_32x32x16_f16(ch[0],  xl0, acc[0][0], 0, 0, 0);
            acc[0][1] = __builtin_amdgcn_mfma_f32_32x32x16_f16(ch[1],  xl0, acc[0][1], 0, 0, 0);
            acc[1][0] = __builtin_amdgcn_mfma_f32_32x32x16_f16(ch[0],  xl1, acc[1][0], 0, 0, 0);
            acc[1][1] = __builtin_amdgcn_mfma_f32_32x32x16_f16(ch[1],  xl1, acc[1][1], 0, 0, 0);
            acc[0][0] = __builtin_amdgcn_mfma_f32_32x32x16_f16(cl2[0], xh0, acc[0][0], 0, 0, 0);
            acc[0][1] = __builtin_amdgcn_mfma_f32_32x32x16_f16(cl2[1], xh0, acc[0][1], 0, 0, 0);
            acc[1][0] = __builtin_amdgcn_mfma_f32_32x32x16_f16(cl2[0], xh1, acc[1][0], 0, 0, 0);
            acc[1][1] = __builtin_amdgcn_mfma_f32_32x32x16_f16(cl2[1], xh1, acc[1][1], 0, 0, 0);
        }

        // epilogue: ne loaded here only (L1-hot after first iter). Code id of
        // acc[ck][mt][r] = code0 + mt*32 + 4*kg + (r&3) + 8*(r>>2); (mt,r)
        // ascending <=> id ascending; strict < => first(lowest-index)-wins.
        f32x4v ne4[2][4];
        #pragma unroll
        for (int mt = 0; mt < 2; ++mt)
            #pragma unroll
            for (int g2 = 0; g2 < 4; ++g2)
                ne4[mt][g2] = *(const f32x4v*)(neF + code0 + mt * 32 + g2 * 8 + 4 * kg);
        #pragma unroll
        for (int ck = 0; ck < 2; ++ck) {
            float best = 3.402823466e+38f;
            int   bi   = 0;
            #pragma unroll
            for (int mt = 0; mt < 2; ++mt)
                #pragma unroll
                for (int r = 0; r < 16; ++r) {
                    float d  = acc[ck][mt][r] + ne4[mt][r >> 2][r & 3];
                    int   id = code0 + mt * 32 + 4 * kg + ((r & 3) + 8 * (r >> 2));
                    if (d < best) { best = d; bi = id; }
                }
            float ov = __shfl_xor(best, 32, 64);
            int   oi = __shfl_xor(bi, 32, 64);
            if (ov < best || (ov == best && oi < bi)) { best = ov; bi = oi; }
            if (kg == 0) {
                int row = (rb0 + ck) * 32 + c32;
                unsigned u = __float_as_uint(best);
                u = (u & 0x80000000u) ? ~u : (u | 0x80000000u);   // total-order map
                atomicMin(&minpair[row],
                          (((unsigned long long)u) << 32) | (unsigned)bi);
            }
        }
    }
}

// decode packed min, gather codebook row, write quantized_sg + float index,
// histogram atomic + per-block SSE partials.
__global__ __launch_bounds__(256) void finalize_kernel(
    const float* __restrict__ x, const float* __restrict__ emb,
    const unsigned long long* __restrict__ minpair,
    float* __restrict__ out_q, float* __restrict__ out_idx,
    int* __restrict__ counts, float* __restrict__ parts) {
    __shared__ float rde[4], rdq[4];
    int wv   = threadIdx.x >> 6;
    int row  = (blockIdx.x << 2) + wv;
    int lane = threadIdx.x & 63;

    int bi = (int)(minpair[row] & 0xFFFFFFFFull);

    float4 xv = ((const float4*)(x   + (size_t)row * DDIM))[lane];
    float4 ev = ((const float4*)(emb + (size_t)bi  * DDIM))[lane];
    float4 q;
    q.x = xv.x + (ev.x - xv.x);
    q.y = xv.y + (ev.y - xv.y);
    q.z = xv.z + (ev.z - xv.z);
    q.w = xv.w + (ev.w - xv.w);
    ((float4*)(out_q + (size_t)row * DDIM))[lane] = q;

    float de = (ev.x - xv.x) * (ev.x - xv.x) + (ev.y - xv.y) * (ev.y - xv.y)
             + (ev.z - xv.z) * (ev.z - xv.z) + (ev.w - xv.w) * (ev.w - xv.w);
    float dq = (q.x - ev.x) * (q.x - ev.x) + (q.y - ev.y) * (q.y - ev.y)
             + (q.z - ev.z) * (q.z - ev.z) + (q.w - ev.w) * (q.w - ev.w);
    #pragma unroll
    for (int m = 32; m; m >>= 1) {
        de += __shfl_xor(de, m, 64);
        dq += __shfl_xor(dq, m, 64);
    }
    if (lane == 0) {
        out_idx[row] = (float)bi;
        atomicAdd(&counts[bi], 1);
        rde[wv] = de; rdq[wv] = dq;
    }
    __syncthreads();
    if (threadIdx.x == 0) {
        parts[blockIdx.x]        = rde[0] + rde[1] + rde[2] + rde[3];
        parts[4096 + blockIdx.x] = rdq[0] + rdq[1] + rdq[2] + rdq[3];
    }
}

__global__ __launch_bounds__(256) void scalars_kernel(
    const int* __restrict__ counts, const float* __restrict__ parts,
    float* __restrict__ out_loss, float* __restrict__ out_perp) {
    __shared__ float red[256], rde[256], rdq[256];
    float local = 0.0f, de = 0.0f, dq = 0.0f;
    for (int k = threadIdx.x; k < KCODES; k += 256) {
        float p = (float)counts[k] * (1.0f / (float)ND_ROWS);
        local += p * logf(p + 1e-10f);
    }
    for (int k = threadIdx.x; k < 4096; k += 256) {
        de += parts[k];
        dq += parts[4096 + k];
    }
    red[threadIdx.x] = local; rde[threadIdx.x] = de; rdq[threadIdx.x] = dq;
    __syncthreads();
    for (int s = 128; s; s >>= 1) {
        if (threadIdx.x < s) {
            red[threadIdx.x] += red[threadIdx.x + s];
            rde[threadIdx.x] += rde[threadIdx.x + s];
            rdq[threadIdx.x] += rdq[threadIdx.x + s];
        }
        __syncthreads();
    }
    if (threadIdx.x == 0) {
        *out_perp = expf(-red[0]);
        float invn = 1.0f / (float)(ND_ROWS * DDIM);
        *out_loss = rdq[0] * invn + 0.25f * (rde[0] * invn);
    }
}

extern "C" void kernel_launch(void* const* d_in, const int* in_sizes, int n_in,
                              void* d_out, int out_size, void* d_ws, size_t ws_size,
                              hipStream_t stream) {
    const float* x   = (const float*)d_in[0];
    const float* emb = (const float*)d_in[1];

    char* ws = (char*)d_ws;
    unsigned long long* minpair = (unsigned long long*)ws;         // 128 KB
    int*      counts = (int*)(ws + 131072);                        // 32 KB
    float*    parts  = (float*)(ws + 163840);                      // 32 KB
    float*    neF    = (float*)(ws + 196608);                      // 32 KB
    _Float16* Xp     = (_Float16*)(ws + 229376);                   // 16.8 MB
    _Float16* Bp     = (_Float16*)(ws + 17006592);                 // 8.4 MB

    float* out_q    = (float*)d_out;
    float* out_idx  = out_q + (size_t)ND_ROWS * DDIM;
    float* out_loss = out_idx + ND_ROWS;
    float* out_perp = out_loss + 1;

    hipMemsetAsync(minpair, 0xFF, ND_ROWS * sizeof(unsigned long long), stream);
    hipMemsetAsync(counts, 0, KCODES * sizeof(int), stream);

    prep_kernel<<<(KCODES + ND_ROWS) / 4, 256, 0, stream>>>(x, emb, Xp, Bp, neF);
    argmin_seg<<<NRG * NSEG, 512, 0, stream>>>(Xp, Bp, neF, minpair);
    finalize_kernel<<<ND_ROWS / 4, 256, 0, stream>>>(x, emb, minpair,
                                                     out_q, out_idx, counts, parts);
    scalars_kernel<<<1, 256, 0, stream>>>(counts, parts, out_loss, out_perp);
}